// Round 1
// baseline (792.226 us; speedup 1.0000x reference)
//
#include <hip/hip_runtime.h>

// DynamicSparseScaledDotProductAttention on MI355X (gfx950)
// q,k,v: [32, 2048, 64] fp32; gate_w: [1,64]; gate_b: [1]
// outputs (tuple): out [32,2048,64] fp32, attn [32,2048,2048] fp32
//
// Two-pass flash-style with recompute: pass1 accumulates softmax denominator
// (no max subtraction: |s| <= ~8, exp is safe in fp32); pass2 recomputes
// scores via bf16 MFMA, writes normalized attn (float4 coalesced) and
// accumulates out = P·V via bf16 MFMA.
//
// MFMA mfma_f32_16x16x32_bf16 layouts (HW-verified per guide):
//   A-frag: lane holds A[m=lane&15][k=(lane>>4)*8 + j], j=0..7
//   B-frag: lane holds B[k=(lane>>4)*8+j][n=lane&15]
//   C/D   : lane holds D[row=(lane>>4)*4 + r][col=lane&15], r=0..3

typedef short bf16x8 __attribute__((ext_vector_type(8)));
typedef float f32x4  __attribute__((ext_vector_type(4)));

#define LSEQ 2048
#define DDIM 64
#define KB_STRIDE 72   // Kbuf row stride (bf16 elems); 144B rows, 16B-aligned, conflict-free
#define VT_STRIDE 36   // Vt row stride (bf16 elems); 72B rows, 8B-aligned
#define PB_STRIDE 36   // Pbuf row stride (f32 elems); 144B rows, 16B-aligned

__device__ __forceinline__ unsigned short f2bf(float x) {
    // round-to-nearest-even fp32 -> bf16
    unsigned int u = __float_as_uint(x);
    u += 0x7FFFu + ((u >> 16) & 1u);
    return (unsigned short)(u >> 16);
}

__global__ __launch_bounds__(256)
void dsa_attn_kernel(const float* __restrict__ Q,
                     const float* __restrict__ K,
                     const float* __restrict__ V,
                     const float* __restrict__ GW,
                     const float* __restrict__ GB,
                     float* __restrict__ OUT,
                     float* __restrict__ ATT)
{
    __shared__ unsigned short Kbuf[32 * KB_STRIDE];   // [key][d] bf16
    __shared__ unsigned short Vt[64 * VT_STRIDE];     // [d][key] bf16 (transposed)
    __shared__ float Pbuf[4][16 * PB_STRIDE];         // per-wave P tile [q][key]
    __shared__ float gateF[64];

    const int bx   = blockIdx.x;
    const int bh   = bx >> 5;            // / (2048/64)
    const int q0   = (bx & 31) << 6;     // * 64
    const int tid  = threadIdx.x;
    const int wave = tid >> 6;
    const int lane = tid & 63;
    const int m16  = lane & 15;
    const int quad = lane >> 4;

    const float* qb = Q + ((size_t)bh * LSEQ + q0) * DDIM;
    const float* kb = K + (size_t)bh * LSEQ * DDIM;
    const float* vb = V + (size_t)bh * LSEQ * DDIM;

    // ---- per-query gate in exact fp32: sigmoid(x) > 0.5  <=>  x > 0 ----
    if (tid < 64) {
        const float* qr = qb + tid * DDIM;
        float a = 0.f;
        #pragma unroll 8
        for (int d = 0; d < DDIM; ++d) a += qr[d] * GW[d];
        a += GB[0];
        gateF[tid] = (a > 0.f) ? 1.f : 0.f;
    }

    // ---- persistent Q A-frags for this wave's 16 queries ----
    bf16x8 qfrag[2];
    {
        const float* qr = qb + ((wave << 4) + m16) * DDIM + (quad << 3);
        #pragma unroll
        for (int db = 0; db < 2; ++db) {
            const float* p = qr + db * 32;
            bf16x8 f;
            #pragma unroll
            for (int j = 0; j < 8; ++j) f[j] = (short)f2bf(p[j]);
            qfrag[db] = f;
        }
    }

    __syncthreads();
    float gate[4];
    int   irow[4];
    #pragma unroll
    for (int r = 0; r < 4; ++r) {
        gate[r] = gateF[(wave << 4) + (quad << 2) + r];
        irow[r] = q0 + (wave << 4) + (quad << 2) + r;
    }

    // =============== pass 1: softmax denominators ===============
    float lsum[4] = {0.f, 0.f, 0.f, 0.f};
    for (int kt = 0; kt < LSEQ / 32; ++kt) {
        __syncthreads();
        {   // stage K tile [32 keys][64 d] -> bf16, coalesced 32B/thread
            const int e   = tid << 3;
            const int key = e >> 6;
            const int d   = e & 63;
            const float* src = kb + (size_t)(kt * 32 + key) * DDIM + d;
            unsigned short* dst = &Kbuf[key * KB_STRIDE + d];
            #pragma unroll
            for (int j = 0; j < 8; ++j) dst[j] = f2bf(src[j]);
        }
        __syncthreads();
        #pragma unroll
        for (int nt = 0; nt < 2; ++nt) {
            const unsigned short* kr = &Kbuf[(nt * 16 + m16) * KB_STRIDE + (quad << 3)];
            bf16x8 kf0 = *(const bf16x8*)(kr);        // d 0..31 slice
            bf16x8 kf1 = *(const bf16x8*)(kr + 32);   // d 32..63 slice
            f32x4 acc = {0.f, 0.f, 0.f, 0.f};
            acc = __builtin_amdgcn_mfma_f32_16x16x32_bf16(qfrag[0], kf0, acc, 0, 0, 0);
            acc = __builtin_amdgcn_mfma_f32_16x16x32_bf16(qfrag[1], kf1, acc, 0, 0, 0);
            const int jcol = kt * 32 + nt * 16 + m16;
            #pragma unroll
            for (int r = 0; r < 4; ++r) {
                int dist = irow[r] - jcol; if (dist < 0) dist = -dist;
                const bool allowed = (gate[r] > 0.5f) || (dist <= 2);
                const float s = acc[r] * 0.125f;
                lsum[r] += allowed ? __expf(s) : 0.f;
            }
        }
    }
    // reduce across the 16 lanes that share this quad's rows
    #pragma unroll
    for (int r = 0; r < 4; ++r) {
        float x = lsum[r];
        x += __shfl_xor(x, 1);
        x += __shfl_xor(x, 2);
        x += __shfl_xor(x, 4);
        x += __shfl_xor(x, 8);
        lsum[r] = 1.0f / x;   // store inverse denominator
    }

    // =============== pass 2: recompute, write attn, accumulate P·V ===============
    f32x4 oacc[4];
    #pragma unroll
    for (int dt = 0; dt < 4; ++dt) oacc[dt] = (f32x4){0.f, 0.f, 0.f, 0.f};

    for (int kt = 0; kt < LSEQ / 32; ++kt) {
        __syncthreads();
        {   // stage K tile
            const int e   = tid << 3;
            const int key = e >> 6;
            const int d   = e & 63;
            const float* src = kb + (size_t)(kt * 32 + key) * DDIM + d;
            unsigned short* dst = &Kbuf[key * KB_STRIDE + d];
            #pragma unroll
            for (int j = 0; j < 8; ++j) dst[j] = f2bf(src[j]);
        }
        {   // stage V tile transposed: Vt[d][key]
            const int key = tid & 31;
            const int db  = (tid >> 5) << 3;
            const float* src = vb + (size_t)(kt * 32 + key) * DDIM + db;
            #pragma unroll
            for (int j = 0; j < 8; ++j)
                Vt[(db + j) * VT_STRIDE + key] = f2bf(src[j]);
        }
        __syncthreads();

        #pragma unroll
        for (int nt = 0; nt < 2; ++nt) {
            const unsigned short* kr = &Kbuf[(nt * 16 + m16) * KB_STRIDE + (quad << 3)];
            bf16x8 kf0 = *(const bf16x8*)(kr);
            bf16x8 kf1 = *(const bf16x8*)(kr + 32);
            f32x4 acc = {0.f, 0.f, 0.f, 0.f};
            acc = __builtin_amdgcn_mfma_f32_16x16x32_bf16(qfrag[0], kf0, acc, 0, 0, 0);
            acc = __builtin_amdgcn_mfma_f32_16x16x32_bf16(qfrag[1], kf1, acc, 0, 0, 0);
            const int jcol = kt * 32 + nt * 16 + m16;
            #pragma unroll
            for (int r = 0; r < 4; ++r) {
                int dist = irow[r] - jcol; if (dist < 0) dist = -dist;
                const bool allowed = (gate[r] > 0.5f) || (dist <= 2);
                const float s = acc[r] * 0.125f;
                const float p = allowed ? __expf(s) * lsum[r] : 0.f;
                Pbuf[wave][((quad << 2) + r) * PB_STRIDE + nt * 16 + m16] = p;
            }
        }
        __syncthreads();

        // C-layout -> A-layout via LDS; doubles as coalesced attn store
        const float* pr = &Pbuf[wave][m16 * PB_STRIDE + (quad << 3)];
        f32x4 p0 = *(const f32x4*)(pr);
        f32x4 p1 = *(const f32x4*)(pr + 4);
        float* ap = ATT + ((size_t)bh * LSEQ + q0 + (wave << 4) + m16) * LSEQ
                        + kt * 32 + (quad << 3);
        *(f32x4*)(ap)     = p0;
        *(f32x4*)(ap + 4) = p1;

        bf16x8 pf;
        #pragma unroll
        for (int j = 0; j < 4; ++j) {
            pf[j]     = (short)f2bf(p0[j]);
            pf[4 + j] = (short)f2bf(p1[j]);
        }
        #pragma unroll
        for (int dt = 0; dt < 4; ++dt) {
            const unsigned short* vr = &Vt[(dt * 16 + m16) * VT_STRIDE + (quad << 3)];
            ushort4 va  = *(const ushort4*)(vr);
            ushort4 vb4 = *(const ushort4*)(vr + 4);
            bf16x8 vf;
            vf[0] = (short)va.x;  vf[1] = (short)va.y;
            vf[2] = (short)va.z;  vf[3] = (short)va.w;
            vf[4] = (short)vb4.x; vf[5] = (short)vb4.y;
            vf[6] = (short)vb4.z; vf[7] = (short)vb4.w;
            oacc[dt] = __builtin_amdgcn_mfma_f32_16x16x32_bf16(pf, vf, oacc[dt], 0, 0, 0);
        }
    }

    // epilogue: out rows in C-layout (P·V used normalized p, so no rescale)
    float* ob = OUT + ((size_t)bh * LSEQ + q0 + (wave << 4)) * DDIM;
    #pragma unroll
    for (int dt = 0; dt < 4; ++dt) {
        #pragma unroll
        for (int r = 0; r < 4; ++r) {
            ob[((quad << 2) + r) * DDIM + dt * 16 + m16] = oacc[dt][r];
        }
    }
}

extern "C" void kernel_launch(void* const* d_in, const int* in_sizes, int n_in,
                              void* d_out, int out_size, void* d_ws, size_t ws_size,
                              hipStream_t stream) {
    const float* q  = (const float*)d_in[0];
    const float* k  = (const float*)d_in[1];
    const float* v  = (const float*)d_in[2];
    const float* gw = (const float*)d_in[3];
    const float* gb = (const float*)d_in[4];

    float* out  = (float*)d_out;                      // [32,2048,64]
    float* attn = out + (size_t)32 * 2048 * 64;       // [32,2048,2048]

    dim3 grid(32 * (2048 / 64));   // 1024 blocks: bh-major, 64 queries each
    dim3 block(256);
    dsa_attn_kernel<<<grid, block, 0, stream>>>(q, k, v, gw, gb, out, attn);
}